// Round 5
// baseline (2136.809 us; speedup 1.0000x reference)
//
#include <hip/hip_runtime.h>
#include <hip/hip_bf16.h>
#include <cmath>

typedef __hip_bfloat16 bf16;
typedef __attribute__((ext_vector_type(8))) short short8;
typedef __attribute__((ext_vector_type(4))) float f32x4;

#define BB 8
#define VV 321
#define SS 24
#define DD 256
#define HH 8
#define GG 10
#define KTOP 33
#define DFFN 1024
#define BV (BB*VV)            // 2568
#define BSEG (BB*SS)          // 192
#define NROWS (BV*SS)         // 61632  (== BSEG*VV)
#define NE ((size_t)NROWS*DD) // 15777792
#define SCALE 0.17677669529663687f  // 1/sqrt(32)
#define LSTR 56               // LDS row stride (bf16): 112B rows, 16B-aligned, 2-way alias max

enum { GF_GELU=1, GF_LOGRELU=2, GF_ABF16=4, GF_RBF16=8, GF_CBF16=16 };
enum { MF_GELU=1, MF_LOGRELU=2, MF_AF32=4, MF_RF32=8, MF_CF32=16, MF_SPLIT=32 };

__device__ __forceinline__ float bf2f(bf16 x){ return __bfloat162float(x); }
__device__ __forceinline__ unsigned short f2bfbits(float f){
  bf16 h = __float2bfloat16(f);
  return *(unsigned short*)&h;
}
__device__ __forceinline__ float bfbits2f(unsigned int u){
  bf16 h; *(unsigned short*)&h = (unsigned short)u; return __bfloat162float(h);
}
__device__ __forceinline__ void ld4bf(const bf16* p, float* f){
  uint2 u = *(const uint2*)p;
  f[0]=bfbits2f(u.x&0xffff); f[1]=bfbits2f(u.x>>16);
  f[2]=bfbits2f(u.y&0xffff); f[3]=bfbits2f(u.y>>16);
}
__device__ __forceinline__ void st4bf(bf16* p, const float* f){
  uint2 u;
  u.x = (unsigned)f2bfbits(f[0]) | ((unsigned)f2bfbits(f[1])<<16);
  u.y = (unsigned)f2bfbits(f[2]) | ((unsigned)f2bfbits(f[3])<<16);
  *(uint2*)p = u;
}

// ---------------------------------------------------------------------------
// Weight prep: fp32 W[K][N] -> bf16 W^T[N][K] into pool. 32x32 tiles via LDS.
// ---------------------------------------------------------------------------
struct WPrep {
  const float* src[12];
  int K[12], N[12], dstoff[12], tileoff[13];
};

__global__ __launch_bounds__(256) void prep_w_k(WPrep p, bf16* __restrict__ pool)
{
  __shared__ float t[32][33];
  int b = blockIdx.x;
  int m = 0;
  while (b >= p.tileoff[m+1]) ++m;
  int tt = b - p.tileoff[m];
  int K = p.K[m], N = p.N[m];
  int nc = N >> 5;
  int tr = tt / nc, tc = tt % nc;      // k-tile, n-tile
  const float* src = p.src[m];
  int tid = threadIdx.x;
  int r = tid >> 3, c = (tid & 7) * 4;
  float4 v = *(const float4*)&src[(size_t)(tr*32 + r)*N + tc*32 + c];
  t[r][c+0]=v.x; t[r][c+1]=v.y; t[r][c+2]=v.z; t[r][c+3]=v.w;
  __syncthreads();
  bf16* dst = pool + p.dstoff[m];
  size_t base = (size_t)(tc*32 + r)*K + tr*32 + c;
  #pragma unroll
  for (int i=0;i<4;++i) dst[base+i] = __float2bfloat16(t[c+i][r]);
}

// ---------------------------------------------------------------------------
// MFMA GEMM: C[M,N] = act(A[M,K] @ W[K,N] + bias) (+ residual)
// A: bf16 (or fp32 w/ MF_AF32), optional log1p(relu) on load.
// Wt: bf16 [N][K] (pre-transposed). bias fp32. C bf16 (or fp32 w/ MF_CF32).
// MF_SPLIT: C column block n>>8 routed to Cp + (n>>8)*splitStride (row len 256),
//           bias selected from bias0/1/2 by n>>8.
// 128x128 tile, BK=32, 256 threads (4 waves), 4x4 16x16x32 MFMAs per wave.
// N multiple of 128; K multiple of 32; M fringe guarded.
// ---------------------------------------------------------------------------
__global__ __launch_bounds__(256) void mgemm_k(
    const void* __restrict__ Ap, const bf16* __restrict__ Wt,
    const float* __restrict__ bias0, const float* __restrict__ bias1,
    const float* __restrict__ bias2, const void* __restrict__ Rp,
    void* __restrict__ Cp, int M, int N, int K, int flags, size_t splitStride)
{
  __shared__ __align__(16) unsigned short As[128*LSTR];
  __shared__ __align__(16) unsigned short Bs[128*LSTR];
  int tid = threadIdx.x;
  int wave = tid >> 6, lane = tid & 63;
  int quad = lane >> 4, l16 = lane & 15;
  int wr = wave >> 1, wc = wave & 1;
  int m0 = blockIdx.y * 128, n0 = blockIdx.x * 128;

  f32x4 acc[4][4];
  #pragma unroll
  for (int i=0;i<4;++i)
    #pragma unroll
    for (int j=0;j<4;++j) acc[i][j] = (f32x4){0.f,0.f,0.f,0.f};

  int r_ = tid >> 2;          // 0..63
  int cg = (tid & 3) * 8;     // elem offset 0,8,16,24

  for (int k0 = 0; k0 < K; k0 += 32) {
    #pragma unroll
    for (int it = 0; it < 2; ++it) {
      int row = r_ + it*64;
      int gm = m0 + row;
      unsigned short v[8];
      if (gm < M) {
        if (flags & MF_AF32) {
          const float* ap = (const float*)Ap + (size_t)gm*K + k0 + cg;
          float4 f0 = *(const float4*)ap;
          float4 f1 = *(const float4*)(ap+4);
          float fv[8] = {f0.x,f0.y,f0.z,f0.w,f1.x,f1.y,f1.z,f1.w};
          #pragma unroll
          for (int j=0;j<8;++j) {
            float f = fv[j];
            if (flags & MF_LOGRELU) f = log1pf(fmaxf(f,0.f));
            v[j] = f2bfbits(f);
          }
        } else {
          const unsigned short* ap = (const unsigned short*)Ap + (size_t)gm*K + k0 + cg;
          uint4 u = *(const uint4*)ap;
          *(uint4*)v = u;
          if (flags & MF_LOGRELU) {
            #pragma unroll
            for (int j=0;j<8;++j) v[j] = f2bfbits(log1pf(fmaxf(bfbits2f(v[j]),0.f)));
          }
        }
      } else {
        #pragma unroll
        for (int j=0;j<8;++j) v[j] = 0;
      }
      *(uint4*)&As[row*LSTR + cg] = *(uint4*)v;
    }
    #pragma unroll
    for (int it = 0; it < 2; ++it) {
      int row = r_ + it*64;
      const unsigned short* wp = (const unsigned short*)Wt + (size_t)(n0+row)*K + k0 + cg;
      *(uint4*)&Bs[row*LSTR + cg] = *(const uint4*)wp;
    }
    __syncthreads();
    short8 a[4], b[4];
    #pragma unroll
    for (int i=0;i<4;++i)
      a[i] = *(const short8*)&As[(wr*64 + i*16 + l16)*LSTR + quad*8];
    #pragma unroll
    for (int j=0;j<4;++j)
      b[j] = *(const short8*)&Bs[(wc*64 + j*16 + l16)*LSTR + quad*8];
    #pragma unroll
    for (int i=0;i<4;++i)
      #pragma unroll
      for (int j=0;j<4;++j)
        acc[i][j] = __builtin_amdgcn_mfma_f32_16x16x32_bf16(a[i], b[j], acc[i][j], 0, 0, 0);
    __syncthreads();
  }

  // ---- epilogue: D[row=quad*4+r][col=l16] per 16x16 tile ----
  #pragma unroll
  for (int i=0;i<4;++i) {
    int mbase = m0 + wr*64 + i*16 + quad*4;
    #pragma unroll
    for (int j=0;j<4;++j) {
      int n = n0 + wc*64 + j*16 + l16;
      float bv;
      if (flags & MF_SPLIT) {
        int sel = n >> 8;
        const float* bp = (sel==0) ? bias0 : (sel==1 ? bias1 : bias2);
        bv = bp[n & 255];
      } else bv = bias0[n];
      #pragma unroll
      for (int r=0;r<4;++r) {
        int mm = mbase + r;
        if (mm >= M) continue;
        float v = acc[i][j][r] + bv;
        if (flags & MF_GELU) v = 0.5f*v*(1.f + erff(v*0.70710678118654752f));
        if (Rp) {
          size_t ri = (size_t)mm*N + n;
          v += (flags & MF_RF32) ? ((const float*)Rp)[ri] : bf2f(((const bf16*)Rp)[ri]);
        }
        if (flags & MF_SPLIT) {
          size_t ci = (size_t)(n>>8)*splitStride + (size_t)mm*256 + (n & 255);
          ((bf16*)Cp)[ci] = __float2bfloat16(v);
        } else {
          size_t ci = (size_t)mm*N + n;
          if (flags & MF_CF32) ((float*)Cp)[ci] = v;
          else                 ((bf16*)Cp)[ci] = __float2bfloat16(v);
        }
      }
    }
  }
}

// ---------------------------------------------------------------------------
// Old fp32 VALU GEMM — kept for the tiny route GEMMs (M<=1920), fp32 in/out.
// ---------------------------------------------------------------------------
__global__ __launch_bounds__(256) void gemm_k(
    const void* __restrict__ Ap, const float* __restrict__ W,
    const float* __restrict__ bias, const void* __restrict__ Rp,
    void* __restrict__ Cp, int M, int N, int K, int flags)
{
  __shared__ float As[16][68];
  __shared__ float Ws[16][68];
  int tid = threadIdx.x;
  int tx = tid & 15, ty = tid >> 4;
  int m0 = blockIdx.y * 64, n0 = blockIdx.x * 64;
  float acc[4][4];
  #pragma unroll
  for (int i=0;i<4;i++)
    #pragma unroll
    for (int j=0;j<4;j++) acc[i][j]=0.f;

  for (int k0 = 0; k0 < K; k0 += 16) {
    #pragma unroll
    for (int i = 0; i < 4; ++i) {
      int idx = tid + i*256;
      int r = idx >> 4, c = idx & 15;
      int gr = m0 + r;
      float v = 0.f;
      if (gr < M) {
        size_t gi = (size_t)gr*K + (size_t)(k0 + c);
        v = (flags & GF_ABF16) ? bf2f(((const bf16*)Ap)[gi]) : ((const float*)Ap)[gi];
        if (flags & GF_LOGRELU) v = log1pf(fmaxf(v, 0.f));
      }
      As[c][r] = v;
    }
    #pragma unroll
    for (int i = 0; i < 4; ++i) {
      int idx = tid + i*256;
      int c = idx >> 6, j = idx & 63;
      Ws[c][j] = W[(size_t)(k0+c)*N + (size_t)(n0 + j)];
    }
    __syncthreads();
    #pragma unroll
    for (int k = 0; k < 16; ++k) {
      float a[4], b[4];
      #pragma unroll
      for (int i=0;i<4;i++) a[i] = As[k][ty*4+i];
      #pragma unroll
      for (int j=0;j<4;j++) b[j] = Ws[k][tx*4+j];
      #pragma unroll
      for (int i=0;i<4;i++)
        #pragma unroll
        for (int j=0;j<4;j++) acc[i][j] = fmaf(a[i], b[j], acc[i][j]);
    }
    __syncthreads();
  }
  #pragma unroll
  for (int i=0;i<4;i++) {
    int row = m0 + ty*4 + i;
    if (row >= M) continue;
    #pragma unroll
    for (int j=0;j<4;j++) {
      int col = n0 + tx*4 + j;
      float v = acc[i][j] + bias[col];
      if (flags & GF_GELU) v = 0.5f*v*(1.f + erff(v*0.70710678118654752f));
      if (Rp) {
        size_t ri = (size_t)row*N + col;
        v += (flags & GF_RBF16) ? bf2f(((const bf16*)Rp)[ri]) : ((const float*)Rp)[ri];
      }
      size_t ci = (size_t)row*N + col;
      if (flags & GF_CBF16) ((bf16*)Cp)[ci] = __float2bfloat16(v);
      else                  ((float*)Cp)[ci] = v;
    }
  }
}

// ---------------------------------------------------------------------------
// Temporal attention v2: one wave per (bv,h). S=24, DH=32. In-place on Q.
// ---------------------------------------------------------------------------
__global__ __launch_bounds__(64) void attn1_k(bf16* __restrict__ Q,
                                              const bf16* __restrict__ Kb,
                                              const bf16* __restrict__ Vb)
{
  int bid = blockIdx.x;            // bv*8 + h
  int bv = bid >> 3, h = bid & 7;
  int lane = threadIdx.x;
  __shared__ float qh[24][33], kh[24][33], vh[24][33];
  __shared__ float sc[24][25];
  const size_t base0 = ((size_t)bv*SS)*DD + h*32;
  #pragma unroll
  for (int it = 0; it < 3; ++it) {
    int t = lane + it*64;          // 0..191
    int r = t >> 3, c4 = (t & 7)*4;
    size_t gi = base0 + (size_t)r*DD + c4;
    ld4bf(Q  + gi, &qh[r][c4]);
    ld4bf(Kb + gi, &kh[r][c4]);
    ld4bf(Vb + gi, &vh[r][c4]);
  }
  __syncthreads();
  #pragma unroll
  for (int it = 0; it < 9; ++it) {
    int t = lane + it*64;          // 0..575
    int i = t / 24, j = t % 24;
    float d = 0.f;
    #pragma unroll
    for (int e = 0; e < 32; ++e) d += qh[i][e]*kh[j][e];
    sc[i][j] = d * SCALE;
  }
  __syncthreads();
  if (lane < 24) {
    float mx = -INFINITY;
    #pragma unroll
    for (int j = 0; j < 24; ++j) mx = fmaxf(mx, sc[lane][j]);
    float sm = 0.f;
    #pragma unroll
    for (int j = 0; j < 24; ++j) { float e = expf(sc[lane][j]-mx); sc[lane][j] = e; sm += e; }
    float inv = 1.f/sm;
    #pragma unroll
    for (int j = 0; j < 24; ++j) sc[lane][j] *= inv;
  }
  __syncthreads();
  #pragma unroll
  for (int it = 0; it < 3; ++it) {
    int t = lane + it*64;
    int r = t >> 3, c4 = (t & 7)*4;
    float o[4] = {0.f,0.f,0.f,0.f};
    #pragma unroll
    for (int j = 0; j < 24; ++j) {
      float p = sc[r][j];
      o[0] += p*vh[j][c4+0]; o[1] += p*vh[j][c4+1];
      o[2] += p*vh[j][c4+2]; o[3] += p*vh[j][c4+3];
    }
    st4bf(Q + base0 + (size_t)r*DD + c4, o);
  }
}

// ---------------------------------------------------------------------------
// LayerNorm: bf16 in/out, fp32 g/b + math. One wave/row, 4 rows/block.
// ---------------------------------------------------------------------------
__global__ __launch_bounds__(256) void ln_k(const bf16* __restrict__ X, bf16* __restrict__ Y,
                                            const float* __restrict__ g, const float* __restrict__ b,
                                            int nrows)
{
  int row = blockIdx.x*4 + (threadIdx.x >> 6);
  int lane = threadIdx.x & 63;
  if (row >= nrows) return;
  const bf16* xr = X + (size_t)row*DD;
  int c = lane*4;
  float v0 = bf2f(xr[c+0]), v1 = bf2f(xr[c+1]), v2 = bf2f(xr[c+2]), v3 = bf2f(xr[c+3]);
  float s = v0+v1+v2+v3;
  #pragma unroll
  for (int off = 32; off; off >>= 1) s += __shfl_xor(s, off);
  float m = s * (1.f/256.f);
  float d0=v0-m, d1=v1-m, d2=v2-m, d3=v3-m;
  float q = d0*d0+d1*d1+d2*d2+d3*d3;
  #pragma unroll
  for (int off = 32; off; off >>= 1) q += __shfl_xor(q, off);
  float rstd = rsqrtf(q*(1.f/256.f) + 1e-5f);
  bf16* yr = Y + (size_t)row*DD;
  yr[c+0] = __float2bfloat16(d0*rstd*g[c+0] + b[c+0]);
  yr[c+1] = __float2bfloat16(d1*rstd*g[c+1] + b[c+1]);
  yr[c+2] = __float2bfloat16(d2*rstd*g[c+2] + b[c+2]);
  yr[c+3] = __float2bfloat16(d3*rstd*g[c+3] + b[c+3]);
}

// LN fused with (B,V,S,D)->(B,S,V,D) permute: write to permuted row.
__global__ __launch_bounds__(256) void ln_t_k(const bf16* __restrict__ X, bf16* __restrict__ Y,
                                              const float* __restrict__ g, const float* __restrict__ b)
{
  int r1 = blockIdx.x*4 + (threadIdx.x >> 6);   // input row (b*321+v)*24+s
  int lane = threadIdx.x & 63;
  if (r1 >= NROWS) return;
  const bf16* xr = X + (size_t)r1*DD;
  int c = lane*4;
  float v0 = bf2f(xr[c+0]), v1 = bf2f(xr[c+1]), v2 = bf2f(xr[c+2]), v3 = bf2f(xr[c+3]);
  float s = v0+v1+v2+v3;
  #pragma unroll
  for (int off = 32; off; off >>= 1) s += __shfl_xor(s, off);
  float m = s * (1.f/256.f);
  float d0=v0-m, d1=v1-m, d2=v2-m, d3=v3-m;
  float q = d0*d0+d1*d1+d2*d2+d3*d3;
  #pragma unroll
  for (int off = 32; off; off >>= 1) q += __shfl_xor(q, off);
  float rstd = rsqrtf(q*(1.f/256.f) + 1e-5f);
  int b_ = r1 / (VV*SS);
  int rem = r1 % (VV*SS);
  int v = rem / SS, ss = rem % SS;
  int r2 = (b_*SS + ss)*VV + v;
  bf16* yr = Y + (size_t)r2*DD;
  yr[c+0] = __float2bfloat16(d0*rstd*g[c+0] + b[c+0]);
  yr[c+1] = __float2bfloat16(d1*rstd*g[c+1] + b[c+1]);
  yr[c+2] = __float2bfloat16(d2*rstd*g[c+2] + b[c+2]);
  yr[c+3] = __float2bfloat16(d3*rstd*g[c+3] + b[c+3]);
}

// Final LN + permute (B,S,V,D)->(B,V,S,D) + fp32 store
__global__ __launch_bounds__(256) void ln_out_k(const bf16* __restrict__ X, float* __restrict__ out,
                                                const float* __restrict__ g, const float* __restrict__ b)
{
  int row = blockIdx.x*4 + (threadIdx.x >> 6);  // row = bs*321+v, bs=b*24+s
  int lane = threadIdx.x & 63;
  if (row >= NROWS) return;
  const bf16* xr = X + (size_t)row*DD;
  int c = lane*4;
  float v0 = bf2f(xr[c+0]), v1 = bf2f(xr[c+1]), v2 = bf2f(xr[c+2]), v3 = bf2f(xr[c+3]);
  float s = v0+v1+v2+v3;
  #pragma unroll
  for (int off = 32; off; off >>= 1) s += __shfl_xor(s, off);
  float m = s * (1.f/256.f);
  float d0=v0-m, d1=v1-m, d2=v2-m, d3=v3-m;
  float q = d0*d0+d1*d1+d2*d2+d3*d3;
  #pragma unroll
  for (int off = 32; off; off >>= 1) q += __shfl_xor(q, off);
  float rstd = rsqrtf(q*(1.f/256.f) + 1e-5f);
  int bs = row / VV, vv = row % VV;
  int bb = bs / SS, ss = bs % SS;
  float* op = out + (((size_t)bb*VV + vv)*SS + ss)*DD + c;
  op[0] = d0*rstd*g[c+0] + b[c+0];
  op[1] = d1*rstd*g[c+1] + b[c+1];
  op[2] = d2*rstd*g[c+2] + b[c+2];
  op[3] = d3*rstd*g[c+3] + b[c+3];
}

// ---------------------------------------------------------------------------
// Scores + top-33 (desc, ties -> lower index). One wave per (bs,h,g).
// ---------------------------------------------------------------------------
__global__ __launch_bounds__(64) void topk_k(const float* __restrict__ qS,
                                             const bf16* __restrict__ kS,
                                             int* __restrict__ idxOut)
{
  int bid = blockIdx.x;                // (bs*8+h)*10+g
  int g = bid % GG;
  int h = (bid / GG) % HH;
  int bs = bid / (GG*HH);
  int s = bs % SS;
  int lane = threadIdx.x;
  __shared__ float qv[32];
  if (lane < 32) qv[lane] = qS[((size_t)(s*GG + g))*DD + h*32 + lane];
  __syncthreads();
  float sc[6];
  #pragma unroll
  for (int j = 0; j < 6; ++j) {
    int v = lane + j*64;
    if (v < VV) {
      const bf16* kp = kS + ((size_t)bs*VV + v)*DD + h*32;
      float d = 0.f;
      #pragma unroll
      for (int e = 0; e < 32; ++e) d += qv[e]*bf2f(kp[e]);
      sc[j] = d * SCALE;
    } else sc[j] = -INFINITY;
  }
  for (int it = 0; it < KTOP; ++it) {
    float bv = sc[0]; int bj = 0;
    #pragma unroll
    for (int j = 1; j < 6; ++j) if (sc[j] > bv) { bv = sc[j]; bj = j; }
    int bi = lane + bj*64;
    #pragma unroll
    for (int off = 32; off; off >>= 1) {
      float ov = __shfl_down(bv, off);
      int   oi = __shfl_down(bi, off);
      if (ov > bv || (ov == bv && oi < bi)) { bv = ov; bi = oi; }
    }
    bi = __shfl(bi, 0);
    if (lane == 0) idxOut[(size_t)bid*KTOP + it] = bi;
    if ((bi & 63) == lane) sc[bi >> 6] = -INFINITY;
  }
}

// ---------------------------------------------------------------------------
// Grouped conv + min/max/exp -> feat (bs,G,256) fp32
// ---------------------------------------------------------------------------
__global__ __launch_bounds__(256) void conv_k(const bf16* __restrict__ vS,
                                              const int* __restrict__ idx,
                                              const float* __restrict__ cw,
                                              const float* __restrict__ cb,
                                              float* __restrict__ feat)
{
  int bid = blockIdx.x;
  int bs = bid / GG, g = bid % GG;
  int tid = threadIdx.x;
  int h = tid >> 5, d = tid & 31;
  __shared__ float cws[KTOP];
  __shared__ int idl[HH][KTOP];
  __shared__ float ms[256];
  if (tid < KTOP) cws[tid] = cw[g*KTOP + tid];
  for (int i = tid; i < HH*KTOP; i += 256) {
    int hh = i / KTOP, k = i % KTOP;
    int ix = idx[(((size_t)bs*HH + hh)*GG + g)*KTOP + k];
    idl[hh][k] = (ix < 0) ? 0 : (ix >= VV ? VV-1 : ix);
  }
  __syncthreads();
  float acc = 0.f;
  #pragma unroll
  for (int k = 0; k < KTOP; ++k)
    acc += bf2f(vS[((size_t)bs*VV + idl[h][k])*DD + h*32 + d]) * cws[k];
  acc += cb[g];
  ms[tid] = acc;
  __syncthreads();
  float mn = acc, mx = acc;
  #pragma unroll
  for (int j = 0; j < 32; ++j) {
    float t = ms[h*32 + j];
    mn = fminf(mn, t); mx = fmaxf(mx, t);
  }
  float xn = expf((acc - mn) / fmaxf(mx - mn, 1e-6f));
  feat[((size_t)bs*GG + g)*DD + h*32 + d] = xn;
}

// ---------------------------------------------------------------------------
// Cross attention (route 2): 321 bf16 queries vs 10 fp32 keys per bs.
// ---------------------------------------------------------------------------
__global__ __launch_bounds__(256) void attn2_k(bf16* __restrict__ Q,
                                               const float* __restrict__ KR,
                                               const float* __restrict__ VR)
{
  int bs = blockIdx.x;
  int tid = threadIdx.x;
  __shared__ float kr[GG][DD], vr[GG][DD];
  for (int i = tid; i < GG*DD; i += 256) {
    int r = i >> 8, c = i & 255;
    kr[r][c] = KR[((size_t)bs*GG + r)*DD + c];
    vr[r][c] = VR[((size_t)bs*GG + r)*DD + c];
  }
  __syncthreads();
  for (int task = tid; task < VV*HH; task += 256) {
    int v = task >> 3, h = task & 7;
    bf16* qp = Q + ((size_t)bs*VV + v)*DD + h*32;
    float qr[32];
    #pragma unroll
    for (int d = 0; d < 32; ++d) qr[d] = bf2f(qp[d]);
    float sv[GG];
    float mx = -INFINITY;
    #pragma unroll
    for (int gi = 0; gi < GG; ++gi) {
      float dsum = 0.f;
      #pragma unroll
      for (int d = 0; d < 32; ++d) dsum += qr[d]*kr[gi][h*32+d];
      sv[gi] = dsum * SCALE;
      mx = fmaxf(mx, sv[gi]);
    }
    float ssum = 0.f;
    #pragma unroll
    for (int gi = 0; gi < GG; ++gi) { sv[gi] = expf(sv[gi]-mx); ssum += sv[gi]; }
    float inv = 1.f/ssum;
    float o[32];
    #pragma unroll
    for (int d = 0; d < 32; ++d) o[d] = 0.f;
    #pragma unroll
    for (int gi = 0; gi < GG; ++gi) {
      float p = sv[gi]*inv;
      #pragma unroll
      for (int d = 0; d < 32; ++d) o[d] += p*vr[gi][h*32+d];
    }
    #pragma unroll
    for (int d = 0; d < 32; ++d) qp[d] = __float2bfloat16(o[d]);
  }
}

// ---------------------------------------------------------------------------
extern "C" void kernel_launch(void* const* d_in, const int* in_sizes, int n_in,
                              void* d_out, int out_size, void* d_ws, size_t ws_size,
                              hipStream_t stream)
{
  const float* queries=(const float*)d_in[0];
  const float* t_wq=(const float*)d_in[1];  const float* t_bq=(const float*)d_in[2];
  const float* t_wk=(const float*)d_in[3];  const float* t_bk=(const float*)d_in[4];
  const float* t_wv=(const float*)d_in[5];  const float* t_bv=(const float*)d_in[6];
  const float* t_wo=(const float*)d_in[7];  const float* t_bo=(const float*)d_in[8];
  const float* s_wq=(const float*)d_in[9];  const float* s_bq=(const float*)d_in[10];
  const float* s_wk=(const float*)d_in[11]; const float* s_bk=(const float*)d_in[12];
  const float* s_wv=(const float*)d_in[13]; const float* s_bv=(const float*)d_in[14];
  const float* s_wo=(const float*)d_in[15]; const float* s_bo=(const float*)d_in[16];
  const float* cluster=(const float*)d_in[17];
  const float* conv_w=(const float*)d_in[18]; const float* conv_b=(const float*)d_in[19];
  const float* r_wq=(const float*)d_in[20]; const float* r_bq=(const float*)d_in[21];
  const float* r_wk=(const float*)d_in[22]; const float* r_bk=(const float*)d_in[23];
  const float* r_wv=(const float*)d_in[24]; const float* r_bv=(const float*)d_in[25];
  const float* r_wo=(const float*)d_in[26]; const float* r_bo=(const float*)d_in[27];
  const float* ln_t1_g=(const float*)d_in[28]; const float* ln_t1_b=(const float*)d_in[29];
  const float* ln_t2_g=(const float*)d_in[30]; const float* ln_t2_b=(const float*)d_in[31];
  const float* ln_d1_g=(const float*)d_in[32]; const float* ln_d1_b=(const float*)d_in[33];
  const float* ln_d2_g=(const float*)d_in[34]; const float* ln_d2_b=(const float*)d_in[35];
  const float* ft_w1=(const float*)d_in[36]; const float* ft_b1=(const float*)d_in[37];
  const float* ft_w2=(const float*)d_in[38]; const float* ft_b2=(const float*)d_in[39];
  const float* fd_w1=(const float*)d_in[40]; const float* fd_b1=(const float*)d_in[41];
  const float* fd_w2=(const float*)d_in[42]; const float* fd_b2=(const float*)d_in[43];

  // Workspace: 3 big bf16 buffers + bf16 W^T pool + fp32 smalls (~108 MB)
  bf16* Ab = (bf16*)d_ws;
  bf16* Bb = Ab + NE;
  bf16* Cb = Bb + NE;
  bf16* WP = Cb + NE;                       // 1572864 bf16
  float* QSf   = (float*)(WP + 1572864);    // 240*256
  float* FEATf = QSf + 240*256;
  float* ROUTEf= FEATf + 1920*256;
  float* KRf   = ROUTEf + 1920*256;
  float* VRf   = KRf + 1920*256;
  int*   IDXb  = (int*)(VRf + 1920*256);    // 15360*33

  // ---- weight prep: fp32 [K][N] -> bf16 [N][K]; QKV and KV groups adjacent ----
  WPrep wp;
  const float* wsrc[12] = {t_wq,t_wk,t_wv,t_wo,s_wk,s_wv,r_wq,r_wo,ft_w1,ft_w2,fd_w1,fd_w2};
  int wK[12] = {256,256,256,256,256,256,256,256,256,1024,256,1024};
  int wN[12] = {256,256,256,256,256,256,256,256,1024,256,1024,256};
  int off = 0, toff = 0;
  for (int i=0;i<12;++i) {
    wp.src[i]=wsrc[i]; wp.K[i]=wK[i]; wp.N[i]=wN[i];
    wp.dstoff[i]=off; wp.tileoff[i]=toff;
    off += wK[i]*wN[i];
    toff += (wK[i]/32)*(wN[i]/32);
  }
  wp.tileoff[12]=toff;
  prep_w_k<<<toff, 256, 0, stream>>>(wp, WP);
  bf16* Wqkv=WP+wp.dstoff[0];               // [768][256]
  bf16* Wo=WP+wp.dstoff[3];
  bf16* Wskv=WP+wp.dstoff[4];               // [512][256]
  bf16* Wrq=WP+wp.dstoff[6]; bf16* Wro=WP+wp.dstoff[7];
  bf16* Wf1=WP+wp.dstoff[8]; bf16* Wf2=WP+wp.dstoff[9];
  bf16* Wd1=WP+wp.dstoff[10]; bf16* Wd2=WP+wp.dstoff[11];

  dim3 blk(256);
  const int STRIPE = NROWS/4;               // 15408
  dim3 gQKV(6, (NROWS+127)/128);            // N=768 merged QKV
  dim3 gKV(4, (NROWS+127)/128);             // N=512 merged s_k/s_v
  dim3 gBig(2, (NROWS+127)/128);            // N=256
  dim3 gS1(8, (STRIPE+127)/128);            // N=1024 FFN up
  dim3 gS2(2, (STRIPE+127)/128);            // N=256  FFN down
  dim3 gQ(4, 4);                            // old kernel, M=240
  dim3 gSmall(4, 30);                       // old kernel, M=1920

  // ---- Route 1: temporal ----
  mgemm_k<<<gQKV, blk, 0, stream>>>(queries, Wqkv, t_bq, t_bk, t_bv, nullptr, Ab,
                                    NROWS, 768, 256, MF_AF32|MF_SPLIT, NE);   // Q->Ab K->Bb V->Cb
  attn1_k<<<BV*HH, 64, 0, stream>>>(Ab, Bb, Cb);                              // O -> Ab (in place)
  mgemm_k<<<gBig, blk, 0, stream>>>(Ab, Wo, t_bo, nullptr, nullptr, queries, Bb,
                                    NROWS, 256, 256, MF_RF32, 0);
  ln_k<<<NROWS/4, blk, 0, stream>>>(Bb, Ab, ln_t1_g, ln_t1_b, NROWS);         // x1 -> Ab
  for (int st = 0; st < 4; ++st) {
    size_t ro = (size_t)st * STRIPE * DD;
    mgemm_k<<<gS1, blk, 0, stream>>>(Ab + ro, Wf1, ft_b1, nullptr, nullptr, nullptr, Cb,
                                     STRIPE, 1024, 256, MF_GELU, 0);
    mgemm_k<<<gS2, blk, 0, stream>>>(Cb, Wf2, ft_b2, nullptr, nullptr, Ab + ro, Bb + ro,
                                     STRIPE, 256, 1024, 0, 0);
  }
  ln_t_k<<<NROWS/4, blk, 0, stream>>>(Bb, Ab, ln_t2_g, ln_t2_b);              // LN+permute -> Ab = xd

  // ---- Route 2: dimensional ----
  mgemm_k<<<gKV, blk, 0, stream>>>(Ab, Wskv, s_bk, s_bv, nullptr, nullptr, Bb,
                                   NROWS, 512, 256, MF_LOGRELU|MF_SPLIT, NE); // kS->Bb vS->Cb
  gemm_k<<<gQ, blk, 0, stream>>>(cluster, s_wq, s_bq, nullptr, QSf, 240, 256, 256, 0);
  topk_k<<<BSEG*HH*GG, 64, 0, stream>>>(QSf, Bb, IDXb);
  conv_k<<<BSEG*GG, blk, 0, stream>>>(Cb, IDXb, conv_w, conv_b, FEATf);
  gemm_k<<<gSmall, blk, 0, stream>>>(FEATf, s_wo, s_bo, nullptr, ROUTEf, 1920, 256, 256, 0);
  gemm_k<<<gSmall, blk, 0, stream>>>(ROUTEf, r_wk, r_bk, nullptr, KRf, 1920, 256, 256, 0);
  gemm_k<<<gSmall, blk, 0, stream>>>(ROUTEf, r_wv, r_bv, nullptr, VRf, 1920, 256, 256, 0);
  mgemm_k<<<gBig, blk, 0, stream>>>(Ab, Wrq, r_bq, nullptr, nullptr, nullptr, Bb,
                                    NROWS, 256, 256, 0, 0);                   // qD -> Bb
  attn2_k<<<BSEG, blk, 0, stream>>>(Bb, KRf, VRf);                            // O -> Bb
  mgemm_k<<<gBig, blk, 0, stream>>>(Bb, Wro, r_bo, nullptr, nullptr, Ab, Cb,
                                    NROWS, 256, 256, 0, 0);                   // + xd -> Cb
  ln_k<<<NROWS/4, blk, 0, stream>>>(Cb, Ab, ln_d1_g, ln_d1_b, NROWS);         // x1d -> Ab
  for (int st = 0; st < 4; ++st) {
    size_t ro = (size_t)st * STRIPE * DD;
    mgemm_k<<<gS1, blk, 0, stream>>>(Ab + ro, Wd1, fd_b1, nullptr, nullptr, nullptr, Bb,
                                     STRIPE, 1024, 256, MF_GELU, 0);
    mgemm_k<<<gS2, blk, 0, stream>>>(Bb, Wd2, fd_b2, nullptr, nullptr, Ab + ro, Cb + ro,
                                     STRIPE, 256, 1024, 0, 0);
  }
  ln_out_k<<<NROWS/4, blk, 0, stream>>>(Cb, (float*)d_out, ln_d2_g, ln_d2_b);
}

// Round 6
// 1861.269 us; speedup vs baseline: 1.1480x; 1.1480x over previous
//
#include <hip/hip_runtime.h>
#include <hip/hip_bf16.h>
#include <cmath>

typedef __hip_bfloat16 bf16;
typedef __attribute__((ext_vector_type(8))) short short8;
typedef __attribute__((ext_vector_type(4))) float f32x4;
typedef unsigned int u32;
typedef __attribute__((address_space(3))) u32 lds_u32;
typedef const __attribute__((address_space(1))) u32 glob_u32;

#define BB 8
#define VV 321
#define SS 24
#define DD 256
#define HH 8
#define GG 10
#define KTOP 33
#define DFFN 1024
#define BV (BB*VV)            // 2568
#define BSEG (BB*SS)          // 192
#define NROWS (BV*SS)         // 61632
#define NE ((size_t)NROWS*DD) // 15777792
#define SCALE 0.17677669529663687f  // 1/sqrt(32)

enum { GF_GELU=1, GF_LOGRELU=2, GF_ABF16=4, GF_RBF16=8, GF_CBF16=16 };
enum { MF_GELU=1, MF_RF32=8, MF_CF32=16, MF_SPLIT=32 };

__device__ __forceinline__ float bf2f(bf16 x){ return __bfloat162float(x); }
__device__ __forceinline__ unsigned short f2bfbits(float f){
  bf16 h = __float2bfloat16(f);
  return *(unsigned short*)&h;
}
__device__ __forceinline__ float bfbits2f(unsigned int u){
  bf16 h; *(unsigned short*)&h = (unsigned short)u; return __bfloat162float(h);
}
__device__ __forceinline__ void ld4bf(const bf16* p, float* f){
  uint2 u = *(const uint2*)p;
  f[0]=bfbits2f(u.x&0xffff); f[1]=bfbits2f(u.x>>16);
  f[2]=bfbits2f(u.y&0xffff); f[3]=bfbits2f(u.y>>16);
}
__device__ __forceinline__ void st4bf(bf16* p, const float* f){
  uint2 u;
  u.x = (unsigned)f2bfbits(f[0]) | ((unsigned)f2bfbits(f[1])<<16);
  u.y = (unsigned)f2bfbits(f[2]) | ((unsigned)f2bfbits(f[3])<<16);
  *(uint2*)p = u;
}
// async 16B global -> LDS (wave-uniform LDS base + lane*16)
__device__ __forceinline__ void gl_lds16(const void* g, void* l){
  __builtin_amdgcn_global_load_lds((glob_u32*)g, (lds_u32*)l, 16, 0, 0);
}

// ---------------------------------------------------------------------------
// Weight prep: fp32 W[K][N] -> bf16 W^T[N][K] into pool. 32x32 tiles via LDS.
// ---------------------------------------------------------------------------
struct WPrep {
  const float* src[12];
  int K[12], N[12], dstoff[12], tileoff[13];
};

__global__ __launch_bounds__(256) void prep_w_k(WPrep p, bf16* __restrict__ pool)
{
  __shared__ float t[32][33];
  int b = blockIdx.x;
  int m = 0;
  while (b >= p.tileoff[m+1]) ++m;
  int tt = b - p.tileoff[m];
  int K = p.K[m], N = p.N[m];
  int nc = N >> 5;
  int tr = tt / nc, tc = tt % nc;
  const float* src = p.src[m];
  int tid = threadIdx.x;
  int r = tid >> 3, c = (tid & 7) * 4;
  float4 v = *(const float4*)&src[(size_t)(tr*32 + r)*N + tc*32 + c];
  t[r][c+0]=v.x; t[r][c+1]=v.y; t[r][c+2]=v.z; t[r][c+3]=v.w;
  __syncthreads();
  bf16* dst = pool + p.dstoff[m];
  size_t base = (size_t)(tc*32 + r)*K + tr*32 + c;
  #pragma unroll
  for (int i=0;i<4;++i) dst[base+i] = __float2bfloat16(t[c+i][r]);
}

// ---------------------------------------------------------------------------
// fp32 -> bf16 bulk convert (8 elems/thread)
// ---------------------------------------------------------------------------
__global__ __launch_bounds__(256) void f2b_k(const float* __restrict__ X, bf16* __restrict__ Y, size_t n)
{
  size_t i = ((size_t)blockIdx.x*256 + threadIdx.x)*8;
  if (i >= n) return;
  float4 a = *(const float4*)(X+i);
  float4 b = *(const float4*)(X+i+4);
  unsigned short v[8] = {f2bfbits(a.x),f2bfbits(a.y),f2bfbits(a.z),f2bfbits(a.w),
                         f2bfbits(b.x),f2bfbits(b.y),f2bfbits(b.z),f2bfbits(b.w)};
  *(uint4*)(Y+i) = *(uint4*)v;
}

// log1p(relu(x)) elementwise bf16->bf16 (8 elems/thread)
__global__ __launch_bounds__(256) void logrelu_k(const bf16* __restrict__ X, bf16* __restrict__ Y, size_t n)
{
  size_t i = ((size_t)blockIdx.x*256 + threadIdx.x)*8;
  if (i >= n) return;
  uint4 u = *(const uint4*)(X+i);
  unsigned short* s = (unsigned short*)&u;
  unsigned short v[8];
  #pragma unroll
  for (int j=0;j<8;++j) v[j] = f2bfbits(log1pf(fmaxf(bfbits2f(s[j]),0.f)));
  *(uint4*)(Y+i) = *(uint4*)v;
}

// ---------------------------------------------------------------------------
// MFMA GEMM v2 (DMA-staged): C[M,N] = act(A[M,K] @ W[K,N] + bias) (+residual)
// A: bf16 [M][K]. Wt: bf16 [N][K] pre-transposed. bias fp32.
// Staging via global_load_lds width 16 into unpadded 128x32 LDS tiles.
// 128x128 tile, BK=32, 256 threads (4 waves), 4x4 16x16x32 MFMAs per wave.
// N multiple of 128; K multiple of 32; M fringe: DMA row clamped, store guarded.
// ---------------------------------------------------------------------------
__global__ __launch_bounds__(256) void mgemm_k(
    const bf16* __restrict__ Ap, const bf16* __restrict__ Wt,
    const float* __restrict__ bias0, const float* __restrict__ bias1,
    const float* __restrict__ bias2, const void* __restrict__ Rp,
    void* __restrict__ Cp, int M, int N, int K, int flags, size_t splitStride)
{
  __shared__ __align__(16) unsigned short As[128*32];
  __shared__ __align__(16) unsigned short Bs[128*32];
  int tid = threadIdx.x;
  int wave = tid >> 6, lane = tid & 63;
  int quad = lane >> 4, l16 = lane & 15;
  int wr = wave >> 1, wc = wave & 1;
  int m0 = blockIdx.y * 128, n0 = blockIdx.x * 128;

  f32x4 acc[4][4];
  #pragma unroll
  for (int i=0;i<4;++i)
    #pragma unroll
    for (int j=0;j<4;++j) acc[i][j] = (f32x4){0.f,0.f,0.f,0.f};

  // staging coords: wave w covers tile rows 32w..32w+31 (two 1KB chunks)
  int r0 = wave*32 + (lane>>2);            // chunk 0 row
  int r1 = r0 + 16;                        // chunk 1 row
  int kc = (lane&3)*8;                     // k elem offset within tile
  int gm0 = m0 + r0; if (gm0 >= M) gm0 = M-1;
  int gm1 = m0 + r1; if (gm1 >= M) gm1 = M-1;
  const bf16* gA0 = Ap + (size_t)gm0*K + kc;
  const bf16* gA1 = Ap + (size_t)gm1*K + kc;
  const bf16* gB0 = Wt + (size_t)(n0 + r0)*K + kc;
  const bf16* gB1 = Wt + (size_t)(n0 + r1)*K + kc;
  unsigned short* lA0 = &As[wave*1024];
  unsigned short* lA1 = &As[wave*1024 + 512];
  unsigned short* lB0 = &Bs[wave*1024];
  unsigned short* lB1 = &Bs[wave*1024 + 512];

  for (int k0 = 0; k0 < K; k0 += 32) {
    gl_lds16(gA0 + k0, lA0);
    gl_lds16(gA1 + k0, lA1);
    gl_lds16(gB0 + k0, lB0);
    gl_lds16(gB1 + k0, lB1);
    __syncthreads();                       // drains vmcnt (compiler-inserted) + barrier
    short8 a[4], b[4];
    #pragma unroll
    for (int i=0;i<4;++i)
      a[i] = *(const short8*)&As[(wr*64 + i*16 + l16)*32 + quad*8];
    #pragma unroll
    for (int j=0;j<4;++j)
      b[j] = *(const short8*)&Bs[(wc*64 + j*16 + l16)*32 + quad*8];
    #pragma unroll
    for (int i=0;i<4;++i)
      #pragma unroll
      for (int j=0;j<4;++j)
        acc[i][j] = __builtin_amdgcn_mfma_f32_16x16x32_bf16(a[i], b[j], acc[i][j], 0, 0, 0);
    __syncthreads();
  }

  // ---- epilogue: D[row=quad*4+r][col=l16] per 16x16 tile ----
  #pragma unroll
  for (int i=0;i<4;++i) {
    int mbase = m0 + wr*64 + i*16 + quad*4;
    #pragma unroll
    for (int j=0;j<4;++j) {
      int n = n0 + wc*64 + j*16 + l16;
      float bv;
      if (flags & MF_SPLIT) {
        int sel = n >> 8;
        const float* bp = (sel==0) ? bias0 : (sel==1 ? bias1 : bias2);
        bv = bp[n & 255];
      } else bv = bias0[n];
      #pragma unroll
      for (int r=0;r<4;++r) {
        int mm = mbase + r;
        if (mm >= M) continue;
        float v = acc[i][j][r] + bv;
        if (flags & MF_GELU) v = 0.5f*v*(1.f + erff(v*0.70710678118654752f));
        if (Rp) {
          size_t ri = (size_t)mm*N + n;
          v += (flags & MF_RF32) ? ((const float*)Rp)[ri] : bf2f(((const bf16*)Rp)[ri]);
        }
        if (flags & MF_SPLIT) {
          size_t ci = (size_t)(n>>8)*splitStride + (size_t)mm*256 + (n & 255);
          ((bf16*)Cp)[ci] = __float2bfloat16(v);
        } else {
          size_t ci = (size_t)mm*N + n;
          if (flags & MF_CF32) ((float*)Cp)[ci] = v;
          else                 ((bf16*)Cp)[ci] = __float2bfloat16(v);
        }
      }
    }
  }
}

// ---------------------------------------------------------------------------
// Old fp32 VALU GEMM — tiny route GEMMs (M<=1920), fp32 in/out.
// ---------------------------------------------------------------------------
__global__ __launch_bounds__(256) void gemm_k(
    const void* __restrict__ Ap, const float* __restrict__ W,
    const float* __restrict__ bias, const void* __restrict__ Rp,
    void* __restrict__ Cp, int M, int N, int K, int flags)
{
  __shared__ float As[16][68];
  __shared__ float Ws[16][68];
  int tid = threadIdx.x;
  int tx = tid & 15, ty = tid >> 4;
  int m0 = blockIdx.y * 64, n0 = blockIdx.x * 64;
  float acc[4][4];
  #pragma unroll
  for (int i=0;i<4;i++)
    #pragma unroll
    for (int j=0;j<4;j++) acc[i][j]=0.f;

  for (int k0 = 0; k0 < K; k0 += 16) {
    #pragma unroll
    for (int i = 0; i < 4; ++i) {
      int idx = tid + i*256;
      int r = idx >> 4, c = idx & 15;
      int gr = m0 + r;
      float v = 0.f;
      if (gr < M) {
        size_t gi = (size_t)gr*K + (size_t)(k0 + c);
        v = (flags & GF_ABF16) ? bf2f(((const bf16*)Ap)[gi]) : ((const float*)Ap)[gi];
        if (flags & GF_LOGRELU) v = log1pf(fmaxf(v, 0.f));
      }
      As[c][r] = v;
    }
    #pragma unroll
    for (int i = 0; i < 4; ++i) {
      int idx = tid + i*256;
      int c = idx >> 6, j = idx & 63;
      Ws[c][j] = W[(size_t)(k0+c)*N + (size_t)(n0 + j)];
    }
    __syncthreads();
    #pragma unroll
    for (int k = 0; k < 16; ++k) {
      float a[4], b[4];
      #pragma unroll
      for (int i=0;i<4;i++) a[i] = As[k][ty*4+i];
      #pragma unroll
      for (int j=0;j<4;j++) b[j] = Ws[k][tx*4+j];
      #pragma unroll
      for (int i=0;i<4;i++)
        #pragma unroll
        for (int j=0;j<4;j++) acc[i][j] = fmaf(a[i], b[j], acc[i][j]);
    }
    __syncthreads();
  }
  #pragma unroll
  for (int i=0;i<4;i++) {
    int row = m0 + ty*4 + i;
    if (row >= M) continue;
    #pragma unroll
    for (int j=0;j<4;j++) {
      int col = n0 + tx*4 + j;
      float v = acc[i][j] + bias[col];
      if (flags & GF_GELU) v = 0.5f*v*(1.f + erff(v*0.70710678118654752f));
      if (Rp) {
        size_t ri = (size_t)row*N + col;
        v += (flags & GF_RBF16) ? bf2f(((const bf16*)Rp)[ri]) : ((const float*)Rp)[ri];
      }
      size_t ci = (size_t)row*N + col;
      if (flags & GF_CBF16) ((bf16*)Cp)[ci] = __float2bfloat16(v);
      else                  ((float*)Cp)[ci] = v;
    }
  }
}

// ---------------------------------------------------------------------------
// Temporal attention: one wave per (bv,h). S=24, DH=32. In-place on Q.
// ---------------------------------------------------------------------------
__global__ __launch_bounds__(64) void attn1_k(bf16* __restrict__ Q,
                                              const bf16* __restrict__ Kb,
                                              const bf16* __restrict__ Vb)
{
  int bid = blockIdx.x;            // bv*8 + h
  int bv = bid >> 3, h = bid & 7;
  int lane = threadIdx.x;
  __shared__ float qh[24][33], kh[24][33], vh[24][33];
  __shared__ float sc[24][25];
  const size_t base0 = ((size_t)bv*SS)*DD + h*32;
  #pragma unroll
  for (int it = 0; it < 3; ++it) {
    int t = lane + it*64;
    int r = t >> 3, c4 = (t & 7)*4;
    size_t gi = base0 + (size_t)r*DD + c4;
    ld4bf(Q  + gi, &qh[r][c4]);
    ld4bf(Kb + gi, &kh[r][c4]);
    ld4bf(Vb + gi, &vh[r][c4]);
  }
  __syncthreads();
  #pragma unroll
  for (int it = 0; it < 9; ++it) {
    int t = lane + it*64;
    int i = t / 24, j = t % 24;
    float d = 0.f;
    #pragma unroll
    for (int e = 0; e < 32; ++e) d += qh[i][e]*kh[j][e];
    sc[i][j] = d * SCALE;
  }
  __syncthreads();
  if (lane < 24) {
    float mx = -INFINITY;
    #pragma unroll
    for (int j = 0; j < 24; ++j) mx = fmaxf(mx, sc[lane][j]);
    float sm = 0.f;
    #pragma unroll
    for (int j = 0; j < 24; ++j) { float e = expf(sc[lane][j]-mx); sc[lane][j] = e; sm += e; }
    float inv = 1.f/sm;
    #pragma unroll
    for (int j = 0; j < 24; ++j) sc[lane][j] *= inv;
  }
  __syncthreads();
  #pragma unroll
  for (int it = 0; it < 3; ++it) {
    int t = lane + it*64;
    int r = t >> 3, c4 = (t & 7)*4;
    float o[4] = {0.f,0.f,0.f,0.f};
    #pragma unroll
    for (int j = 0; j < 24; ++j) {
      float p = sc[r][j];
      o[0] += p*vh[j][c4+0]; o[1] += p*vh[j][c4+1];
      o[2] += p*vh[j][c4+2]; o[3] += p*vh[j][c4+3];
    }
    st4bf(Q + base0 + (size_t)r*DD + c4, o);
  }
}

// ---------------------------------------------------------------------------
// LayerNorm family
// ---------------------------------------------------------------------------
__global__ __launch_bounds__(256) void ln_k(const bf16* __restrict__ X, bf16* __restrict__ Y,
                                            const float* __restrict__ g, const float* __restrict__ b,
                                            int nrows)
{
  int row = blockIdx.x*4 + (threadIdx.x >> 6);
  int lane = threadIdx.x & 63;
  if (row >= nrows) return;
  const bf16* xr = X + (size_t)row*DD;
  int c = lane*4;
  float v0 = bf2f(xr[c+0]), v1 = bf2f(xr[c+1]), v2 = bf2f(xr[c+2]), v3 = bf2f(xr[c+3]);
  float s = v0+v1+v2+v3;
  #pragma unroll
  for (int off = 32; off; off >>= 1) s += __shfl_xor(s, off);
  float m = s * (1.f/256.f);
  float d0=v0-m, d1=v1-m, d2=v2-m, d3=v3-m;
  float q = d0*d0+d1*d1+d2*d2+d3*d3;
  #pragma unroll
  for (int off = 32; off; off >>= 1) q += __shfl_xor(q, off);
  float rstd = rsqrtf(q*(1.f/256.f) + 1e-5f);
  bf16* yr = Y + (size_t)row*DD;
  yr[c+0] = __float2bfloat16(d0*rstd*g[c+0] + b[c+0]);
  yr[c+1] = __float2bfloat16(d1*rstd*g[c+1] + b[c+1]);
  yr[c+2] = __float2bfloat16(d2*rstd*g[c+2] + b[c+2]);
  yr[c+3] = __float2bfloat16(d3*rstd*g[c+3] + b[c+3]);
}

// LN fused with (B,V,S,D)->(B,S,V,D) permute
__global__ __launch_bounds__(256) void ln_t_k(const bf16* __restrict__ X, bf16* __restrict__ Y,
                                              const float* __restrict__ g, const float* __restrict__ b)
{
  int r1 = blockIdx.x*4 + (threadIdx.x >> 6);
  int lane = threadIdx.x & 63;
  if (r1 >= NROWS) return;
  const bf16* xr = X + (size_t)r1*DD;
  int c = lane*4;
  float v0 = bf2f(xr[c+0]), v1 = bf2f(xr[c+1]), v2 = bf2f(xr[c+2]), v3 = bf2f(xr[c+3]);
  float s = v0+v1+v2+v3;
  #pragma unroll
  for (int off = 32; off; off >>= 1) s += __shfl_xor(s, off);
  float m = s * (1.f/256.f);
  float d0=v0-m, d1=v1-m, d2=v2-m, d3=v3-m;
  float q = d0*d0+d1*d1+d2*d2+d3*d3;
  #pragma unroll
  for (int off = 32; off; off >>= 1) q += __shfl_xor(q, off);
  float rstd = rsqrtf(q*(1.f/256.f) + 1e-5f);
  int b_ = r1 / (VV*SS);
  int rem = r1 % (VV*SS);
  int v = rem / SS, ss = rem % SS;
  int r2 = (b_*SS + ss)*VV + v;
  bf16* yr = Y + (size_t)r2*DD;
  yr[c+0] = __float2bfloat16(d0*rstd*g[c+0] + b[c+0]);
  yr[c+1] = __float2bfloat16(d1*rstd*g[c+1] + b[c+1]);
  yr[c+2] = __float2bfloat16(d2*rstd*g[c+2] + b[c+2]);
  yr[c+3] = __float2bfloat16(d3*rstd*g[c+3] + b[c+3]);
}

// Final LN + permute (B,S,V,D)->(B,V,S,D) + fp32 store
__global__ __launch_bounds__(256) void ln_out_k(const bf16* __restrict__ X, float* __restrict__ out,
                                                const float* __restrict__ g, const float* __restrict__ b)
{
  int row = blockIdx.x*4 + (threadIdx.x >> 6);
  int lane = threadIdx.x & 63;
  if (row >= NROWS) return;
  const bf16* xr = X + (size_t)row*DD;
  int c = lane*4;
  float v0 = bf2f(xr[c+0]), v1 = bf2f(xr[c+1]), v2 = bf2f(xr[c+2]), v3 = bf2f(xr[c+3]);
  float s = v0+v1+v2+v3;
  #pragma unroll
  for (int off = 32; off; off >>= 1) s += __shfl_xor(s, off);
  float m = s * (1.f/256.f);
  float d0=v0-m, d1=v1-m, d2=v2-m, d3=v3-m;
  float q = d0*d0+d1*d1+d2*d2+d3*d3;
  #pragma unroll
  for (int off = 32; off; off >>= 1) q += __shfl_xor(q, off);
  float rstd = rsqrtf(q*(1.f/256.f) + 1e-5f);
  int bs = row / VV, vv = row % VV;
  int bb = bs / SS, ss = bs % SS;
  float* op = out + (((size_t)bb*VV + vv)*SS + ss)*DD + c;
  op[0] = d0*rstd*g[c+0] + b[c+0];
  op[1] = d1*rstd*g[c+1] + b[c+1];
  op[2] = d2*rstd*g[c+2] + b[c+2];
  op[3] = d3*rstd*g[c+3] + b[c+3];
}

// ---------------------------------------------------------------------------
// Scores + top-33 (desc, ties -> lower index). One wave per (bs,h,g).
// ---------------------------------------------------------------------------
__global__ __launch_bounds__(64) void topk_k(const float* __restrict__ qS,
                                             const bf16* __restrict__ kS,
                                             int* __restrict__ idxOut)
{
  int bid = blockIdx.x;                // (bs*8+h)*10+g
  int g = bid % GG;
  int h = (bid / GG) % HH;
  int bs = bid / (GG*HH);
  int s = bs % SS;
  int lane = threadIdx.x;
  __shared__ float qv[32];
  if (lane < 32) qv[lane] = qS[((size_t)(s*GG + g))*DD + h*32 + lane];
  __syncthreads();
  float sc[6];
  #pragma unroll
  for (int j = 0; j < 6; ++j) {
    int v = lane + j*64;
    if (v < VV) {
      const bf16* kp = kS + ((size_t)bs*VV + v)*DD + h*32;
      float d = 0.f;
      #pragma unroll
      for (int e = 0; e < 32; ++e) d += qv[e]*bf2f(kp[e]);
      sc[j] = d * SCALE;
    } else sc[j] = -INFINITY;
  }
  for (int it = 0; it < KTOP; ++it) {
    float bv = sc[0]; int bj = 0;
    #pragma unroll
    for (int j = 1; j < 6; ++j) if (sc[j] > bv) { bv = sc[j]; bj = j; }
    int bi = lane + bj*64;
    #pragma unroll
    for (int off = 32; off; off >>= 1) {
      float ov = __shfl_down(bv, off);
      int   oi = __shfl_down(bi, off);
      if (ov > bv || (ov == bv && oi < bi)) { bv = ov; bi = oi; }
    }
    bi = __shfl(bi, 0);
    if (lane == 0) idxOut[(size_t)bid*KTOP + it] = bi;
    if ((bi & 63) == lane) sc[bi >> 6] = -INFINITY;
  }
}

// ---------------------------------------------------------------------------
// Grouped conv + min/max/exp -> feat (bs,G,256) fp32
// ---------------------------------------------------------------------------
__global__ __launch_bounds__(256) void conv_k(const bf16* __restrict__ vS,
                                              const int* __restrict__ idx,
                                              const float* __restrict__ cw,
                                              const float* __restrict__ cb,
                                              float* __restrict__ feat)
{
  int bid = blockIdx.x;
  int bs = bid / GG, g = bid % GG;
  int tid = threadIdx.x;
  int h = tid >> 5, d = tid & 31;
  __shared__ float cws[KTOP];
  __shared__ int idl[HH][KTOP];
  __shared__ float ms[256];
  if (tid < KTOP) cws[tid] = cw[g*KTOP + tid];
  for (int i = tid; i < HH*KTOP; i += 256) {
    int hh = i / KTOP, k = i % KTOP;
    int ix = idx[(((size_t)bs*HH + hh)*GG + g)*KTOP + k];
    idl[hh][k] = (ix < 0) ? 0 : (ix >= VV ? VV-1 : ix);
  }
  __syncthreads();
  float acc = 0.f;
  #pragma unroll
  for (int k = 0; k < KTOP; ++k)
    acc += bf2f(vS[((size_t)bs*VV + idl[h][k])*DD + h*32 + d]) * cws[k];
  acc += cb[g];
  ms[tid] = acc;
  __syncthreads();
  float mn = acc, mx = acc;
  #pragma unroll
  for (int j = 0; j < 32; ++j) {
    float t = ms[h*32 + j];
    mn = fminf(mn, t); mx = fmaxf(mx, t);
  }
  float xn = expf((acc - mn) / fmaxf(mx - mn, 1e-6f));
  feat[((size_t)bs*GG + g)*DD + h*32 + d] = xn;
}

// ---------------------------------------------------------------------------
// Cross attention (route 2): 321 bf16 queries vs 10 fp32 keys per bs.
// ---------------------------------------------------------------------------
__global__ __launch_bounds__(256) void attn2_k(bf16* __restrict__ Q,
                                               const float* __restrict__ KR,
                                               const float* __restrict__ VR)
{
  int bs = blockIdx.x;
  int tid = threadIdx.x;
  __shared__ float kr[GG][DD], vr[GG][DD];
  for (int i = tid; i < GG*DD; i += 256) {
    int r = i >> 8, c = i & 255;
    kr[r][c] = KR[((size_t)bs*GG + r)*DD + c];
    vr[r][c] = VR[((size_t)bs*GG + r)*DD + c];
  }
  __syncthreads();
  for (int task = tid; task < VV*HH; task += 256) {
    int v = task >> 3, h = task & 7;
    bf16* qp = Q + ((size_t)bs*VV + v)*DD + h*32;
    float qr[32];
    #pragma unroll
    for (int d = 0; d < 32; ++d) qr[d] = bf2f(qp[d]);
    float sv[GG];
    float mx = -INFINITY;
    #pragma unroll
    for (int gi = 0; gi < GG; ++gi) {
      float dsum = 0.f;
      #pragma unroll
      for (int d = 0; d < 32; ++d) dsum += qr[d]*kr[gi][h*32+d];
      sv[gi] = dsum * SCALE;
      mx = fmaxf(mx, sv[gi]);
    }
    float ssum = 0.f;
    #pragma unroll
    for (int gi = 0; gi < GG; ++gi) { sv[gi] = expf(sv[gi]-mx); ssum += sv[gi]; }
    float inv = 1.f/ssum;
    float o[32];
    #pragma unroll
    for (int d = 0; d < 32; ++d) o[d] = 0.f;
    #pragma unroll
    for (int gi = 0; gi < GG; ++gi) {
      float p = sv[gi]*inv;
      #pragma unroll
      for (int d = 0; d < 32; ++d) o[d] += p*vr[gi][h*32+d];
    }
    #pragma unroll
    for (int d = 0; d < 32; ++d) qp[d] = __float2bfloat16(o[d]);
  }
}

// ---------------------------------------------------------------------------
extern "C" void kernel_launch(void* const* d_in, const int* in_sizes, int n_in,
                              void* d_out, int out_size, void* d_ws, size_t ws_size,
                              hipStream_t stream)
{
  const float* queries=(const float*)d_in[0];
  const float* t_wq=(const float*)d_in[1];  const float* t_bq=(const float*)d_in[2];
  const float* t_wk=(const float*)d_in[3];  const float* t_bk=(const float*)d_in[4];
  const float* t_wv=(const float*)d_in[5];  const float* t_bv=(const float*)d_in[6];
  const float* t_wo=(const float*)d_in[7];  const float* t_bo=(const float*)d_in[8];
  const float* s_wq=(const float*)d_in[9];  const float* s_bq=(const float*)d_in[10];
  const float* s_wk=(const float*)d_in[11]; const float* s_bk=(const float*)d_in[12];
  const float* s_wv=(const float*)d_in[13]; const float* s_bv=(const float*)d_in[14];
  const float* s_wo=(const float*)d_in[15]; const float* s_bo=(const float*)d_in[16];
  const float* cluster=(const float*)d_in[17];
  const float* conv_w=(const float*)d_in[18]; const float* conv_b=(const float*)d_in[19];
  const float* r_wq=(const float*)d_in[20]; const float* r_bq=(const float*)d_in[21];
  const float* r_wk=(const float*)d_in[22]; const float* r_bk=(const float*)d_in[23];
  const float* r_wv=(const float*)d_in[24]; const float* r_bv=(const float*)d_in[25];
  const float* r_wo=(const float*)d_in[26]; const float* r_bo=(const float*)d_in[27];
  const float* ln_t1_g=(const float*)d_in[28]; const float* ln_t1_b=(const float*)d_in[29];
  const float* ln_t2_g=(const float*)d_in[30]; const float* ln_t2_b=(const float*)d_in[31];
  const float* ln_d1_g=(const float*)d_in[32]; const float* ln_d1_b=(const float*)d_in[33];
  const float* ln_d2_g=(const float*)d_in[34]; const float* ln_d2_b=(const float*)d_in[35];
  const float* ft_w1=(const float*)d_in[36]; const float* ft_b1=(const float*)d_in[37];
  const float* ft_w2=(const float*)d_in[38]; const float* ft_b2=(const float*)d_in[39];
  const float* fd_w1=(const float*)d_in[40]; const float* fd_b1=(const float*)d_in[41];
  const float* fd_w2=(const float*)d_in[42]; const float* fd_b2=(const float*)d_in[43];

  // Workspace: 4 big bf16 buffers (126 MB) + W^T pool (3 MB) + smalls (~10 MB)
  bf16* Ab = (bf16*)d_ws;
  bf16* Bb = Ab + NE;
  bf16* Cb = Bb + NE;
  bf16* Db = Cb + NE;                       // queries-bf16 (route1) / xl (route2)
  bf16* WP = Db + NE;                       // 1572864 bf16
  float* QSf   = (float*)(WP + 1572864);
  float* FEATf = QSf + 240*256;
  float* ROUTEf= FEATf + 1920*256;
  float* KRf   = ROUTEf + 1920*256;
  float* VRf   = KRf + 1920*256;
  int*   IDXb  = (int*)(VRf + 1920*256);

  // ---- weight prep ----
  WPrep wp;
  const float* wsrc[12] = {t_wq,t_wk,t_wv,t_wo,s_wk,s_wv,r_wq,r_wo,ft_w1,ft_w2,fd_w1,fd_w2};
  int wK[12] = {256,256,256,256,256,256,256,256,256,1024,256,1024};
  int wN[12] = {256,256,256,256,256,256,256,256,1024,256,1024,256};
  int off = 0, toff = 0;
  for (int i=0;i<12;++i) {
    wp.src[i]=wsrc[i]; wp.K[i]=wK[i]; wp.N[i]=wN[i];
    wp.dstoff[i]=off; wp.tileoff[i]=toff;
    off += wK[i]*wN[i];
    toff += (wK[i]/32)*(wN[i]/32);
  }
  wp.tileoff[12]=toff;
  prep_w_k<<<toff, 256, 0, stream>>>(wp, WP);
  bf16* Wqkv=WP+wp.dstoff[0];               // [768][256]
  bf16* Wo=WP+wp.dstoff[3];
  bf16* Wskv=WP+wp.dstoff[4];               // [512][256]
  bf16* Wrq=WP+wp.dstoff[6]; bf16* Wro=WP+wp.dstoff[7];
  bf16* Wf1=WP+wp.dstoff[8]; bf16* Wf2=WP+wp.dstoff[9];
  bf16* Wd1=WP+wp.dstoff[10]; bf16* Wd2=WP+wp.dstoff[11];

  dim3 blk(256);
  const int STRIPE = NROWS/4;               // 15408
  dim3 gQKV(6, (NROWS+127)/128);
  dim3 gKV(4, (NROWS+127)/128);
  dim3 gBig(2, (NROWS+127)/128);
  dim3 gS1(8, (STRIPE+127)/128);
  dim3 gS2(2, (STRIPE+127)/128);
  dim3 gQ(4, 4);
  dim3 gSmall(4, 30);
  const int GCVT = (int)(NE/2048);          // 7704

  // ---- Route 1: temporal ----
  f2b_k<<<GCVT, blk, 0, stream>>>(queries, Db, NE);
  mgemm_k<<<gQKV, blk, 0, stream>>>(Db, Wqkv, t_bq, t_bk, t_bv, nullptr, Ab,
                                    NROWS, 768, 256, MF_SPLIT, NE);           // Q->Ab K->Bb V->Cb
  attn1_k<<<BV*HH, 64, 0, stream>>>(Ab, Bb, Cb);                              // O -> Ab
  mgemm_k<<<gBig, blk, 0, stream>>>(Ab, Wo, t_bo, nullptr, nullptr, queries, Bb,
                                    NROWS, 256, 256, MF_RF32, 0);
  ln_k<<<NROWS/4, blk, 0, stream>>>(Bb, Ab, ln_t1_g, ln_t1_b, NROWS);
  for (int st = 0; st < 4; ++st) {
    size_t ro = (size_t)st * STRIPE * DD;
    mgemm_k<<<gS1, blk, 0, stream>>>(Ab + ro, Wf1, ft_b1, nullptr, nullptr, nullptr, Cb,
                                     STRIPE, 1024, 256, MF_GELU, 0);
    mgemm_k<<<gS2, blk, 0, stream>>>(Cb, Wf2, ft_b2, nullptr, nullptr, Ab + ro, Bb + ro,
                                     STRIPE, 256, 1024, 0, 0);
  }
  ln_t_k<<<NROWS/4, blk, 0, stream>>>(Bb, Ab, ln_t2_g, ln_t2_b);              // xd -> Ab

  // ---- Route 2: dimensional ----
  logrelu_k<<<GCVT, blk, 0, stream>>>(Ab, Db, NE);                            // xl -> Db
  mgemm_k<<<gKV, blk, 0, stream>>>(Db, Wskv, s_bk, s_bv, nullptr, nullptr, Bb,
                                   NROWS, 512, 256, MF_SPLIT, NE);            // kS->Bb vS->Cb
  gemm_k<<<gQ, blk, 0, stream>>>(cluster, s_wq, s_bq, nullptr, QSf, 240, 256, 256, 0);
  topk_k<<<BSEG*HH*GG, 64, 0, stream>>>(QSf, Bb, IDXb);
  conv_k<<<BSEG*GG, blk, 0, stream>>>(Cb, IDXb, conv_w, conv_b, FEATf);
  gemm_k<<<gSmall, blk, 0, stream>>>(FEATf, s_wo, s_bo, nullptr, ROUTEf, 1920, 256, 256, 0);
  gemm_k<<<gSmall, blk, 0, stream>>>(ROUTEf, r_wk, r_bk, nullptr, KRf, 1920, 256, 256, 0);
  gemm_k<<<gSmall, blk, 0, stream>>>(ROUTEf, r_wv, r_bv, nullptr, VRf, 1920, 256, 256, 0);
  mgemm_k<<<gBig, blk, 0, stream>>>(Ab, Wrq, r_bq, nullptr, nullptr, nullptr, Bb,
                                    NROWS, 256, 256, 0, 0);                   // qD -> Bb
  attn2_k<<<BSEG, blk, 0, stream>>>(Bb, KRf, VRf);                            // O -> Bb
  mgemm_k<<<gBig, blk, 0, stream>>>(Bb, Wro, r_bo, nullptr, nullptr, Ab, Cb,
                                    NROWS, 256, 256, 0, 0);                   // + xd -> Cb
  ln_k<<<NROWS/4, blk, 0, stream>>>(Cb, Ab, ln_d1_g, ln_d1_b, NROWS);
  for (int st = 0; st < 4; ++st) {
    size_t ro = (size_t)st * STRIPE * DD;
    mgemm_k<<<gS1, blk, 0, stream>>>(Ab + ro, Wd1, fd_b1, nullptr, nullptr, nullptr, Bb,
                                     STRIPE, 1024, 256, MF_GELU, 0);
    mgemm_k<<<gS2, blk, 0, stream>>>(Bb, Wd2, fd_b2, nullptr, nullptr, Ab + ro, Cb + ro,
                                     STRIPE, 256, 1024, 0, 0);
  }
  ln_out_k<<<NROWS/4, blk, 0, stream>>>(Cb, (float*)d_out, ln_d2_g, ln_d2_b);
}